// Round 3
// baseline (27653.574 us; speedup 1.0000x reference)
//
#include <hip/hip_runtime.h>
#include <hip/hip_bf16.h>

// Problem constants: B,SE,SD,E,H,V,O
constexpr int kB  = 16;
constexpr int kSE = 128;
constexpr int kSD = 128;
constexpr int kE  = 512;
constexpr int kH  = 1024;
constexpr int kO  = 32000;

using f32x4  = __attribute__((ext_vector_type(4))) float;
using bf16x8 = __attribute__((ext_vector_type(8))) short;

// ---------------------------------------------------------------------------
// Gather embedding rows: out[r,:] = emb[idx[r],:], row len E=512
// ---------------------------------------------------------------------------
__global__ __launch_bounds__(128) void gather_rows(
    const float* __restrict__ emb, const int* __restrict__ idx,
    float* __restrict__ out)
{
    int r = blockIdx.x;
    int t = threadIdx.x;
    const float4* src = (const float4*)(emb + (size_t)idx[r] * kE);
    float4* dst = (float4*)(out + (size_t)r * kE);
    dst[t] = src[t];
}

// ---------------------------------------------------------------------------
// Generalized 1024x1024 transpose: out[k*kH + j] = in[j*ldin + coff + k]
// ---------------------------------------------------------------------------
__global__ __launch_bounds__(256) void transpose_k(
    const float* __restrict__ in, int ldin, int coff, float* __restrict__ out)
{
    __shared__ float tile[32][33];
    int bx = blockIdx.x * 32, by = blockIdx.y * 32;   // bx: j, by: k
    int tx = threadIdx.x, ty = threadIdx.y;           // block (32,8)
    for (int i = ty; i < 32; i += 8)
        tile[i][tx] = in[(size_t)(bx + i) * ldin + coff + by + tx];
    __syncthreads();
    for (int i = ty; i < 32; i += 8)
        out[(size_t)(by + i) * kH + bx + tx] = tile[tx][i];
}

// ---------------------------------------------------------------------------
// f32 NT GEMM (verified round 1): C = A * B^T (+bias)
// ---------------------------------------------------------------------------
constexpr int BM = 128, BN = 128, BK = 16, LDP = 132;

__global__ __launch_bounds__(256, 2) void gemm_nt(
    const float* __restrict__ A, int lda,
    const float* __restrict__ Bmat, int ldb,
    float* __restrict__ C, int ldc,
    const float* __restrict__ bias, int K)
{
    __shared__ float As[BK][LDP];
    __shared__ float Bs[BK][LDP];

    const int bn = blockIdx.x, bm = blockIdx.y;
    const int tid = threadIdx.x;
    const int tm = tid & 15;
    const int tn = tid >> 4;

    const float* Ab = A    + (size_t)bm * BM * lda;
    const float* Bb = Bmat + (size_t)bn * BN * ldb;

    const int sr = tid >> 1;
    const int sc = (tid & 1) * 8;

    float acc[8][8];
    #pragma unroll
    for (int i = 0; i < 8; ++i)
        #pragma unroll
        for (int j = 0; j < 8; ++j) acc[i][j] = 0.f;

    for (int k0 = 0; k0 < K; k0 += BK) {
        const float4 a0 = *(const float4*)(Ab + (size_t)sr * lda + k0 + sc);
        const float4 a1 = *(const float4*)(Ab + (size_t)sr * lda + k0 + sc + 4);
        const float4 b0 = *(const float4*)(Bb + (size_t)sr * ldb + k0 + sc);
        const float4 b1 = *(const float4*)(Bb + (size_t)sr * ldb + k0 + sc + 4);
        __syncthreads();
        As[sc + 0][sr] = a0.x; As[sc + 1][sr] = a0.y;
        As[sc + 2][sr] = a0.z; As[sc + 3][sr] = a0.w;
        As[sc + 4][sr] = a1.x; As[sc + 5][sr] = a1.y;
        As[sc + 6][sr] = a1.z; As[sc + 7][sr] = a1.w;
        Bs[sc + 0][sr] = b0.x; Bs[sc + 1][sr] = b0.y;
        Bs[sc + 2][sr] = b0.z; Bs[sc + 3][sr] = b0.w;
        Bs[sc + 4][sr] = b1.x; Bs[sc + 5][sr] = b1.y;
        Bs[sc + 6][sr] = b1.z; Bs[sc + 7][sr] = b1.w;
        __syncthreads();

        #pragma unroll
        for (int k = 0; k < BK; ++k) {
            const float4 fa0 = *(const float4*)&As[k][tm * 8];
            const float4 fa1 = *(const float4*)&As[k][tm * 8 + 4];
            const float4 fb0 = *(const float4*)&Bs[k][tn * 8];
            const float4 fb1 = *(const float4*)&Bs[k][tn * 8 + 4];
            const float am[8] = {fa0.x, fa0.y, fa0.z, fa0.w,
                                 fa1.x, fa1.y, fa1.z, fa1.w};
            const float bb[8] = {fb0.x, fb0.y, fb0.z, fb0.w,
                                 fb1.x, fb1.y, fb1.z, fb1.w};
            #pragma unroll
            for (int i = 0; i < 8; ++i)
                #pragma unroll
                for (int j = 0; j < 8; ++j)
                    acc[i][j] += am[i] * bb[j];
        }
    }

    float bv[8];
    if (bias) {
        const float4 t0 = *(const float4*)&bias[bn * BN + tn * 8];
        const float4 t1 = *(const float4*)&bias[bn * BN + tn * 8 + 4];
        bv[0] = t0.x; bv[1] = t0.y; bv[2] = t0.z; bv[3] = t0.w;
        bv[4] = t1.x; bv[5] = t1.y; bv[6] = t1.z; bv[7] = t1.w;
    } else {
        #pragma unroll
        for (int j = 0; j < 8; ++j) bv[j] = 0.f;
    }
    #pragma unroll
    for (int i = 0; i < 8; ++i) {
        const size_t row = (size_t)(bm * BM + tm * 8 + i);
        float* cp = C + row * (size_t)ldc + bn * BN + tn * 8;
        float4 o0 = {acc[i][0] + bv[0], acc[i][1] + bv[1],
                     acc[i][2] + bv[2], acc[i][3] + bv[3]};
        float4 o1 = {acc[i][4] + bv[4], acc[i][5] + bv[5],
                     acc[i][6] + bv[6], acc[i][7] + bv[7]};
        *(float4*)cp = o0;
        *(float4*)(cp + 4) = o1;
    }
}

// ---------------------------------------------------------------------------
// cb[r] = dot(M[r,:], v) — one wave per row
// ---------------------------------------------------------------------------
__global__ __launch_bounds__(256) void dot_bias(
    const float* __restrict__ Mrows, const float* __restrict__ v,
    float* __restrict__ out)
{
    int w = (blockIdx.x * blockDim.x + threadIdx.x) >> 6;
    int lane = threadIdx.x & 63;
    const float* row = Mrows + (size_t)w * kH;
    float s = 0.f;
    for (int k = lane; k < kH; k += 64) s += row[k] * v[k];
    #pragma unroll
    for (int off = 32; off > 0; off >>= 1) s += __shfl_xor(s, off);
    if (lane == 0) out[w] = s;
}

// ---------------------------------------------------------------------------
// init: ht0[j][b] = hrow0[b][j] = state0[b][j]
// ---------------------------------------------------------------------------
__global__ __launch_bounds__(1024) void init_h(
    const float* __restrict__ s0, float* __restrict__ ht0,
    float* __restrict__ hrow0)
{
    int b = blockIdx.x, j = threadIdx.x;
    float v = s0[b * kH + j];
    ht0[j * 16 + b] = v;
    hrow0[b * kH + j] = v;
}

// ---------------------------------------------------------------------------
// Encoder step v2: coalesced WhhT[k][j] stream + broadcast ht[k][b].
// grid (8 j-tiles of 128, 8 b-pairs), block 128. 2 batch elems per thread.
// ---------------------------------------------------------------------------
__global__ __launch_bounds__(128) void enc_step2(
    const float* __restrict__ X, const float* __restrict__ WhhT,
    const float* __restrict__ ht_in, float* __restrict__ ht_out,
    float* __restrict__ hrow_out, float* __restrict__ EH, int t)
{
    const int j  = blockIdx.x * 128 + threadIdx.x;
    const int b0 = blockIdx.y * 2;
    float a0 = 0.f, a1 = 0.f;
    #pragma unroll 8
    for (int k = 0; k < kH; ++k) {
        const float w = WhhT[(size_t)k * kH + j];
        const float2 hv = *(const float2*)(ht_in + k * 16 + b0);
        a0 += w * hv.x;
        a1 += w * hv.y;
    }
    const float r0 = tanhf(X[((size_t)b0 * kSE + t) * kH + j] + a0);
    const float r1 = tanhf(X[((size_t)(b0 + 1) * kSE + t) * kH + j] + a1);
    ht_out[j * 16 + b0]     = r0;
    ht_out[j * 16 + b0 + 1] = r1;
    hrow_out[(size_t)b0 * kH + j]       = r0;
    hrow_out[(size_t)(b0 + 1) * kH + j] = r1;
    EH[((size_t)b0 * kSE + t) * kH + j]       = r0;
    EH[((size_t)(b0 + 1) * kSE + t) * kH + j] = r1;
}

// ---------------------------------------------------------------------------
// Decoder attention v2 (one block of 1024 per batch element):
//   scores -> softmax -> ctx (written transposed [j][b])
// ---------------------------------------------------------------------------
__global__ __launch_bounds__(1024) void attn_step2(
    const float* __restrict__ Aw, const float* __restrict__ cbv,
    const float* __restrict__ hrow, const float* __restrict__ EH,
    float* __restrict__ ctx_t)
{
    __shared__ float hl[kH];
    __shared__ float sc[kSE];
    const int b = blockIdx.x;
    const int tid = threadIdx.x;
    const int lane = tid & 63;
    const int w = tid >> 6;          // 16 waves

    hl[tid] = hrow[(size_t)b * kH + tid];
    __syncthreads();

    #pragma unroll
    for (int i = 0; i < 8; ++i) {    // each wave: 8 scores
        const int s = w * 8 + i;
        const float* ar = Aw + ((size_t)b * kSE + s) * kH;
        float p = 0.f;
        #pragma unroll
        for (int it = 0; it < 4; ++it) {
            const int k = it * 256 + lane * 4;
            const float4 av = *(const float4*)(ar + k);
            const float4 hv = *(const float4*)(hl + k);
            p += av.x * hv.x + av.y * hv.y + av.z * hv.z + av.w * hv.w;
        }
        #pragma unroll
        for (int off = 32; off > 0; off >>= 1) p += __shfl_xor(p, off);
        if (lane == 0) sc[s] = p + cbv[b * kSE + s];
    }
    __syncthreads();

    if (w == 0) {                    // wave 0: softmax over 128 scores
        float v0 = sc[lane], v1 = sc[lane + 64];
        float m = fmaxf(v0, v1);
        #pragma unroll
        for (int off = 32; off > 0; off >>= 1) m = fmaxf(m, __shfl_xor(m, off));
        const float e0 = expf(v0 - m), e1 = expf(v1 - m);
        float s = e0 + e1;
        #pragma unroll
        for (int off = 32; off > 0; off >>= 1) s += __shfl_xor(s, off);
        const float inv = 1.f / s;
        sc[lane] = e0 * inv;
        sc[lane + 64] = e1 * inv;
    }
    __syncthreads();

    float acc = 0.f;
    #pragma unroll 8
    for (int s = 0; s < kSE; ++s)
        acc += sc[s] * EH[((size_t)b * kSE + s) * kH + tid];
    ctx_t[tid * 16 + b] = acc;
}

// ---------------------------------------------------------------------------
// Decoder hidden step v2: two coalesced weight streams + broadcast ht/ctx.
// ---------------------------------------------------------------------------
__global__ __launch_bounds__(128) void dec_step2(
    const float* __restrict__ X, const float* __restrict__ WhhT,
    const float* __restrict__ WcT, const float* __restrict__ ht_in,
    const float* __restrict__ ctx_t, float* __restrict__ ht_out,
    float* __restrict__ hrow_out, float* __restrict__ Hs, int t)
{
    const int j  = blockIdx.x * 128 + threadIdx.x;
    const int b0 = blockIdx.y * 2;
    float a0 = 0.f, a1 = 0.f;
    #pragma unroll 4
    for (int k = 0; k < kH; ++k) {
        const float wh = WhhT[(size_t)k * kH + j];
        const float wc = WcT [(size_t)k * kH + j];
        const float2 hv = *(const float2*)(ht_in + k * 16 + b0);
        const float2 cv = *(const float2*)(ctx_t + k * 16 + b0);
        a0 += wh * hv.x + wc * cv.x;
        a1 += wh * hv.y + wc * cv.y;
    }
    const float r0 = tanhf(X[((size_t)b0 * kSD + t) * kH + j] + a0);
    const float r1 = tanhf(X[((size_t)(b0 + 1) * kSD + t) * kH + j] + a1);
    ht_out[j * 16 + b0]     = r0;
    ht_out[j * 16 + b0 + 1] = r1;
    hrow_out[(size_t)b0 * kH + j]       = r0;
    hrow_out[(size_t)(b0 + 1) * kH + j] = r1;
    Hs[((size_t)b0 * kSD + t) * kH + j]       = r0;
    Hs[((size_t)(b0 + 1) * kSD + t) * kH + j] = r1;
}

// ---------------------------------------------------------------------------
// bf16 MFMA NT GEMM: C[M x N] f32 = A[M x K]f32 * B[N x K]f32^T + bias.
// 128x128 tile, BK=32, 256 threads = 4 waves in 2x2 quadrants of 64x64.
// Reg-staged f32 -> bf16 conversion into LDS. M%128==0, N%128==0, K%32==0.
// ---------------------------------------------------------------------------
__device__ __forceinline__ unsigned pk_bf16(float x, float y) {
    union { float f; unsigned u; } a{x}, b{y};
    unsigned ra = (a.u + 0x7fffu + ((a.u >> 16) & 1u)) >> 16;   // RNE
    unsigned rb = (b.u + 0x7fffu + ((b.u >> 16) & 1u)) >> 16;
    return (ra & 0xffffu) | (rb << 16);
}

constexpr int GBK = 32;

__global__ __launch_bounds__(256) void gemm_bf16_nt(
    const float* __restrict__ A, int lda,
    const float* __restrict__ Bmat, int ldb,
    float* __restrict__ C, int ldc,
    const float* __restrict__ bias, int K)
{
    __shared__ short As[128 * GBK];   // [row][k], row stride 32 bf16 (64B)
    __shared__ short Bs[128 * GBK];

    const int tid  = threadIdx.x;
    const int wave = tid >> 6, lane = tid & 63;
    const int wr = wave >> 1, wc = wave & 1;            // 2x2 quadrants
    const int bm = blockIdx.y, bn = blockIdx.x;

    const float* Ab = A    + (size_t)bm * 128 * lda;
    const float* Bb = Bmat + (size_t)bn * 128 * ldb;

    const int srow = tid >> 1;                          // 0..127
    const int sk   = (tid & 1) * 16;                    // 0 or 16

    const int frow = lane & 15;                         // fragment row/col
    const int kgrp = lane >> 4;                         // 0..3 k-group of 8

    f32x4 acc[4][4];
    #pragma unroll
    for (int m = 0; m < 4; ++m)
        #pragma unroll
        for (int n = 0; n < 4; ++n) acc[m][n] = (f32x4)(0.f);

    for (int k0 = 0; k0 < K; k0 += GBK) {
        const float* ap = Ab + (size_t)srow * lda + k0 + sk;
        const float* bp = Bb + (size_t)srow * ldb + k0 + sk;
        const float4 a0 = *(const float4*)(ap);
        const float4 a1 = *(const float4*)(ap + 4);
        const float4 a2 = *(const float4*)(ap + 8);
        const float4 a3 = *(const float4*)(ap + 12);
        const float4 b0 = *(const float4*)(bp);
        const float4 b1 = *(const float4*)(bp + 4);
        const float4 b2 = *(const float4*)(bp + 8);
        const float4 b3 = *(const float4*)(bp + 12);
        __syncthreads();                                // prev tile consumed
        int4 wA0 = {(int)pk_bf16(a0.x, a0.y), (int)pk_bf16(a0.z, a0.w),
                    (int)pk_bf16(a1.x, a1.y), (int)pk_bf16(a1.z, a1.w)};
        int4 wA1 = {(int)pk_bf16(a2.x, a2.y), (int)pk_bf16(a2.z, a2.w),
                    (int)pk_bf16(a3.x, a3.y), (int)pk_bf16(a3.z, a3.w)};
        int4 wB0 = {(int)pk_bf16(b0.x, b0.y), (int)pk_bf16(b0.z, b0.w),
                    (int)pk_bf16(b1.x, b1.y), (int)pk_bf16(b1.z, b1.w)};
        int4 wB1 = {(int)pk_bf16(b2.x, b2.y), (int)pk_bf16(b2.z, b2.w),
                    (int)pk_bf16(b3.x, b3.y), (int)pk_bf16(b3.z, b3.w)};
        *(int4*)&As[srow * GBK + sk]     = wA0;
        *(int4*)&As[srow * GBK + sk + 8] = wA1;
        *(int4*)&Bs[srow * GBK + sk]     = wB0;
        *(int4*)&Bs[srow * GBK + sk + 8] = wB1;
        __syncthreads();

        bf16x8 af[4], bf[4];
        #pragma unroll
        for (int m = 0; m < 4; ++m)
            af[m] = *(const bf16x8*)&As[(wr * 64 + m * 16 + frow) * GBK + kgrp * 8];
        #pragma unroll
        for (int n = 0; n < 4; ++n)
            bf[n] = *(const bf16x8*)&Bs[(wc * 64 + n * 16 + frow) * GBK + kgrp * 8];
        #pragma unroll
        for (int m = 0; m < 4; ++m)
            #pragma unroll
            for (int n = 0; n < 4; ++n)
                acc[m][n] = __builtin_amdgcn_mfma_f32_16x16x32_bf16(
                    af[m], bf[n], acc[m][n], 0, 0, 0);
    }

    // Epilogue: C/D layout col = lane&15, row = (lane>>4)*4 + reg  [m89]
    float bv[4];
    #pragma unroll
    for (int n = 0; n < 4; ++n)
        bv[n] = bias ? bias[bn * 128 + wc * 64 + n * 16 + frow] : 0.f;
    #pragma unroll
    for (int m = 0; m < 4; ++m) {
        #pragma unroll
        for (int n = 0; n < 4; ++n) {
            const int col = bn * 128 + wc * 64 + n * 16 + frow;
            #pragma unroll
            for (int r = 0; r < 4; ++r) {
                const int row = bm * 128 + wr * 64 + m * 16 + kgrp * 4 + r;
                C[(size_t)row * ldc + col] = acc[m][n][r] + bv[n];
            }
        }
    }
}

// ---------------------------------------------------------------------------
extern "C" void kernel_launch(void* const* d_in, const int* in_sizes, int n_in,
                              void* d_out, int out_size, void* d_ws, size_t ws_size,
                              hipStream_t stream)
{
    const int*   enc_x   = (const int*)  d_in[0];
    const int*   dec_y   = (const int*)  d_in[1];
    const float* state0  = (const float*)d_in[2];
    const float* emb     = (const float*)d_in[3];
    const float* enc_Wih = (const float*)d_in[4];
    const float* enc_Whh = (const float*)d_in[5];
    const float* enc_b   = (const float*)d_in[6];
    const float* mlp1_W  = (const float*)d_in[7];
    const float* mlp1_b  = (const float*)d_in[8];
    const float* dec_Wih = (const float*)d_in[9];
    const float* dec_Whh = (const float*)d_in[10];
    const float* dec_b   = (const float*)d_in[11];
    const float* mlp2_W  = (const float*)d_in[12];
    const float* mlp2_b  = (const float*)d_in[13];
    float* out = (float*)d_out;

    // Workspace layout (floats). Total ~13.09M floats ≈ 52.4 MB — matches the
    // footprint that passed in round 1. Buffers are aliased where lifetimes
    // are disjoint (stream-ordered, single stream):
    //   EncEmb -> WhhTe   (EncEmb dead after enc input-projection GEMM)
    //   DecEmb -> WhhTd   (DecEmb dead after dec input-projection GEMM)
    //   W1T    -> Hs[0:1M] (W1T dead after step-5 GEMM; Hs written in step 6)
    float* ws = (float*)d_ws;
    size_t off = 0;
    const int R = kB * kSE;                            // 2048 rows (b*128+t)
    float* Xenc   = ws + off; off += (size_t)R * kH;   // 2M
    float* Xdec   = ws + off; off += (size_t)R * kH;   // 2M
    float* EH     = ws + off; off += (size_t)R * kH;   // 2M
    float* Aw     = ws + off; off += (size_t)R * kH;   // 2M
    float* Hs     = ws + off; off += (size_t)R * kH;   // 2M (W1T aliased below)
    float* W1T    = Hs;                                //   1M alias
    float* WcT    = ws + off; off += (size_t)kH * kH;  // 1M
    float* EncEmb = ws + off; off += (size_t)R * kE;   // 1M (WhhTe aliased)
    float* WhhTe  = EncEmb;
    float* DecEmb = ws + off; off += (size_t)R * kE;   // 1M (WhhTd aliased)
    float* WhhTd  = DecEmb;
    float* cbv    = ws + off; off += R;
    float* ht0    = ws + off; off += kB * kH;
    float* ht1    = ws + off; off += kB * kH;
    float* hrow0  = ws + off; off += kB * kH;
    float* hrow1  = ws + off; off += kB * kH;
    float* ctxT   = ws + off; off += kB * kH;
    float* htb[2]   = {ht0, ht1};
    float* hrowb[2] = {hrow0, hrow1};

    // 1) embedding gathers
    gather_rows<<<R, 128, 0, stream>>>(emb, enc_x, EncEmb);
    gather_rows<<<R, 128, 0, stream>>>(emb, dec_y, DecEmb);

    // 2) input projections for all timesteps (hoisted out of the scans) —
    //    these consume EncEmb/DecEmb, freeing them for the weight transposes
    gemm_nt<<<dim3(kH / BN, R / BM), 256, 0, stream>>>(
        EncEmb, kE, enc_Wih, kE, Xenc, kH, enc_b, kE);
    gemm_nt<<<dim3(kH / BN, R / BM), 256, 0, stream>>>(
        DecEmb, kE, dec_Wih, kE + kH, Xdec, kH, dec_b, kE);

    // 3) weight transposes into the freed regions + W1T into Hs region
    transpose_k<<<dim3(32, 32), dim3(32, 8), 0, stream>>>(enc_Whh, kH, 0, WhhTe);
    transpose_k<<<dim3(32, 32), dim3(32, 8), 0, stream>>>(dec_Whh, kH, 0, WhhTd);
    transpose_k<<<dim3(32, 32), dim3(32, 8), 0, stream>>>(dec_Wih, kE + kH, kE, WcT);
    transpose_k<<<dim3(32, 32), dim3(32, 8), 0, stream>>>(mlp1_W, kH, 0, W1T);

    // 4) h0
    init_h<<<kB, kH, 0, stream>>>(state0, ht0, hrow0);

    // 5) encoder scan (final state lands in index 0 after 128 steps)
    for (int t = 0; t < kSE; ++t) {
        enc_step2<<<dim3(8, 8), 128, 0, stream>>>(
            Xenc, WhhTe, htb[t & 1], htb[(t + 1) & 1], hrowb[(t + 1) & 1], EH, t);
    }

    // 6) attention precompute: Aw = EH @ mlp1_W, cbv = EH @ mlp1_b
    //    (reads W1T from the Hs region — Hs is not written until step 7)
    gemm_nt<<<dim3(kH / BN, R / BM), 256, 0, stream>>>(
        EH, kH, W1T, kH, Aw, kH, nullptr, kH);
    dot_bias<<<R / 4, 256, 0, stream>>>(EH, mlp1_b, cbv);

    // 7) decoder scan
    for (int t = 0; t < kSD; ++t) {
        attn_step2<<<kB, 1024, 0, stream>>>(
            Aw, cbv, hrowb[t & 1], EH, ctxT);
        dec_step2<<<dim3(8, 8), 128, 0, stream>>>(
            Xdec, WhhTd, WcT, htb[t & 1], ctxT,
            htb[(t + 1) & 1], hrowb[(t + 1) & 1], Hs, t);
    }

    // 8) batched output projection (bf16 MFMA): out = Hs @ mlp2_W^T + mlp2_b
    gemm_bf16_nt<<<dim3(kO / 128, R / 128), 256, 0, stream>>>(
        Hs, kH, mlp2_W, kH, out, kO, mlp2_b, kH);
}